// Round 3
// baseline (730.489 us; speedup 1.0000x reference)
//
#include <hip/hip_runtime.h>

#define NN 50000
#define NE 1600000
#define NR 8
#define ND 128
#define NL 3
#define RN (NR * NN)
#define SCAN_BLK 1024
#define NB ((RN + SCAN_BLK - 1) / SCAN_BLK)  // 391
#define LN_EPS 1e-5f
#define PADF 132   // f32 elems per epilogue scratch row (8448 B per wave region)

// fused prep kernel region sizes
#define PREP_G (NN * 64)        // gather dwords
#define PREP_W (27 * 16384)     // wprep elems
#define PREP_TOT (RN + PREP_G + PREP_W)

// workspace layout
#define WS_H    0
#define WS_CNT  12800000
#define WS_ROW  14400000
#define WS_BSUM 16000064
#define WS_BOFF 16002048
#define WS_ADJ  16004096
#define WS_WB   22404096
#define WS_BIG  23288832
#define WS_NEED_NEW (23288832ULL + 9ULL * NN * 256)   // hr = 9 tables -> 138.5 MB

typedef __attribute__((ext_vector_type(8))) short short8;
typedef __attribute__((ext_vector_type(4))) float float4v;
typedef __attribute__((ext_vector_type(4))) unsigned uint4v;

__device__ __forceinline__ float bflo(unsigned u) { return __uint_as_float(u << 16); }
__device__ __forceinline__ float bfhi(unsigned u) { return __uint_as_float(u & 0xFFFF0000u); }
__device__ __forceinline__ unsigned f2bf(float f) {
    unsigned u = __float_as_uint(f);
    return (u + 0x7FFFu + ((u >> 16) & 1u)) >> 16;   // RNE
}
__device__ __forceinline__ unsigned pack2(float lo, float hi) {
    return f2bf(lo) | (f2bf(hi) << 16);
}

// fused: cnt zero | h gather (row-major bf16x2) | weight prep (B-frag layout)
__global__ __launch_bounds__(256) void k_prep0(const int* __restrict__ x,
                                               const float* __restrict__ emb,
                                               const float* __restrict__ w_rel,
                                               const float* __restrict__ w_root,
                                               int* __restrict__ cnt,
                                               unsigned* __restrict__ h,
                                               unsigned short* __restrict__ wb) {
    int i = blockIdx.x * 256 + threadIdx.x;
    if (i < RN) {
        cnt[i] = 0;
        return;
    }
    i -= RN;
    if (i < PREP_G) {
        int n = i >> 6, dw = i & 63;
        float2 v = *(const float2*)&emb[(size_t)x[n] * ND + 2 * dw];
        h[i] = pack2(v.x, v.y);
        return;
    }
    i -= PREP_G;
    if (i >= PREP_W) return;
    int m = i >> 14;
    int idx = i & 16383;
    int j = idx & 7;
    int lane = (idx >> 3) & 63;
    int ft = (idx >> 9) & 7;
    int kk = idx >> 12;
    int row = kk * 32 + (lane >> 4) * 8 + j;
    int col = ft * 16 + (lane & 15);
    const float* W = (m < 24) ? (w_rel + (size_t)m * 16384)
                              : (w_root + (size_t)(m - 24) * 16384);
    wb[i] = (unsigned short)f2bf(W[row * ND + col]);
}

__global__ __launch_bounds__(256) void k_count(const int* __restrict__ dst,
                                               const int* __restrict__ et,
                                               int* __restrict__ cnt) {
    int i = blockIdx.x * 256 + threadIdx.x;
    if (i >= NE / 4) return;
    int4 d4 = ((const int4*)dst)[i];
    int4 t4 = ((const int4*)et)[i];
    atomicAdd(&cnt[t4.x * NN + d4.x], 1);
    atomicAdd(&cnt[t4.y * NN + d4.y], 1);
    atomicAdd(&cnt[t4.z * NN + d4.z], 1);
    atomicAdd(&cnt[t4.w * NN + d4.w], 1);
}

// scan over cnt -> rowstart (exclusive)
__global__ __launch_bounds__(256) void k_scan1(const int* __restrict__ cnt,
                                               int* __restrict__ rowstart,
                                               int* __restrict__ bsum) {
    __shared__ int tmp[256];
    int t = threadIdx.x;
    int base = blockIdx.x * SCAN_BLK + t * 4;
    int v[4];
#pragma unroll
    for (int i = 0; i < 4; i++) v[i] = (base + i < RN) ? cnt[base + i] : 0;
    int local = v[0] + v[1] + v[2] + v[3];
    tmp[t] = local;
    __syncthreads();
    for (int off = 1; off < 256; off <<= 1) {
        int x = (t >= off) ? tmp[t - off] : 0;
        __syncthreads();
        tmp[t] += x;
        __syncthreads();
    }
    int run = tmp[t] - local;
    if (t == 255) bsum[blockIdx.x] = tmp[t];
#pragma unroll
    for (int i = 0; i < 4; i++) {
        if (base + i < RN) rowstart[base + i] = run;
        run += v[i];
    }
}

__global__ __launch_bounds__(256) void k_scan2(const int* __restrict__ bsum,
                                               int* __restrict__ boff) {
    __shared__ int tmp[256];
    int t = threadIdx.x;
    int v0 = (2 * t < NB) ? bsum[2 * t] : 0;
    int v1 = (2 * t + 1 < NB) ? bsum[2 * t + 1] : 0;
    int local = v0 + v1;
    tmp[t] = local;
    __syncthreads();
    for (int off = 1; off < 256; off <<= 1) {
        int x = (t >= off) ? tmp[t - off] : 0;
        __syncthreads();
        tmp[t] += x;
        __syncthreads();
    }
    int excl = tmp[t] - local;
    if (2 * t < NB) boff[2 * t] = excl;
    if (2 * t + 1 < NB) boff[2 * t + 1] = excl + v0;
}

__global__ __launch_bounds__(256) void k_scan3(int* __restrict__ rowstart,
                                               const int* __restrict__ boff) {
    int i = blockIdx.x * 256 + threadIdx.x;
    if (i < RN) rowstart[i] += boff[i >> 10];
    if (i == 0) rowstart[RN] = NE;
}

// Plain stores (nt-store regressed 88->110: no L2 merging, full latency per
// store; WRITE_SIZE is line-count-driven either way). This is the scatter floor.
__global__ __launch_bounds__(256) void k_fill(const int* __restrict__ src,
                                              const int* __restrict__ dst,
                                              const int* __restrict__ et,
                                              const int* __restrict__ rowstart,
                                              int* __restrict__ cnt,
                                              int* __restrict__ adj) {
    int i = blockIdx.x * 256 + threadIdx.x;
    if (i >= NE / 4) return;
    int4 s4 = ((const int4*)src)[i];
    int4 d4 = ((const int4*)dst)[i];
    int4 t4 = ((const int4*)et)[i];
    int seg, c;
    seg = t4.x * NN + d4.x; c = atomicSub(&cnt[seg], 1); adj[rowstart[seg] + c - 1] = s4.x;
    seg = t4.y * NN + d4.y; c = atomicSub(&cnt[seg], 1); adj[rowstart[seg] + c - 1] = s4.y;
    seg = t4.z * NN + d4.z; c = atomicSub(&cnt[seg], 1); adj[rowstart[seg] + c - 1] = s4.z;
    seg = t4.w * NN + d4.w; c = atomicSub(&cnt[seg], 1); adj[rowstart[seg] + c - 1] = s4.w;
}

// ---------- NEW PATH: transform-first (reference order), no S round-trip ----

// k_mm: hr[m] = h @ W_m for m in {0..7 rel, 8 root}. Dense GEMM, B staged in
// LDS per block. Epilogue: C cols are lane-interleaved (col=ft*16+l15), so
// pack bf16x2 via one shfl_xor(1) per acc reg (pairs adjacent columns);
// parity-balanced stores. hr rows are feature-linear bf16x2, 256 B each.
__global__ __launch_bounds__(256) void k_mm(const unsigned* __restrict__ h32,
                                            const unsigned short* __restrict__ wrel,
                                            const unsigned short* __restrict__ wroot,
                                            unsigned* __restrict__ hr) {
    __shared__ uint4 SB4[2048];                      // 32 KB B stage
    const unsigned short* SBs = (const unsigned short*)SB4;

    int tid = threadIdx.x;
    int wave = tid >> 6, lane = tid & 63;
    int quad = lane >> 4, l15 = lane & 15;
    int w0w = blockIdx.x * 64 + wave * 16;
    int gi = w0w + l15; gi = gi < NN ? gi : NN - 1;
    int pr = l15 & 1;

    const unsigned* Hrow = h32 + (size_t)gi * 64;
    short8 afr[4];
#pragma unroll
    for (int kk = 0; kk < 4; kk++)
        afr[kk] = *(const short8*)&Hrow[kk * 16 + quad * 4];

    for (int m = 0; m < 9; m++) {
        const unsigned short* W = (m < 8) ? (wrel + (size_t)m * 16384) : wroot;
        __syncthreads();                             // prev m's SB reads done
        {
            const uint4* Wg = (const uint4*)W;
#pragma unroll
            for (int i = 0; i < 8; i++) SB4[tid + 256 * i] = Wg[tid + 256 * i];
        }
        __syncthreads();

        float4v acc[8];
#pragma unroll
        for (int i = 0; i < 8; i++) acc[i] = (float4v){0.f, 0.f, 0.f, 0.f};
#pragma unroll
        for (int kk = 0; kk < 4; kk++) {
#pragma unroll
            for (int ft = 0; ft < 8; ft++) {
                short8 bf = *(const short8*)&SBs[((kk * 8 + ft) * 64 + lane) * 8];
                acc[ft] = __builtin_amdgcn_mfma_f32_16x16x32_bf16(afr[kk], bf, acc[ft], 0, 0, 0);
            }
        }

        unsigned* hrm = hr + (size_t)m * NN * 64;
#pragma unroll
        for (int ft = 0; ft < 8; ft++) {
            float4v part;
#pragma unroll
            for (int rg = 0; rg < 4; rg++) part[rg] = __shfl_xor(acc[ft][rg], 1, 64);
            if ((ft & 1) == pr) {                    // parity-balanced emit
                int a = l15 >> 1;
#pragma unroll
                for (int rg = 0; rg < 4; rg++) {
                    int row = w0w + quad * 4 + rg;
                    if (row < NN) {
                        float lo = pr ? part[rg] : acc[ft][rg];   // even col
                        float hi = pr ? acc[ft][rg] : part[rg];   // odd col
                        __builtin_nontemporal_store(pack2(lo, hi),
                            &hrm[(size_t)row * 64 + ft * 8 + a]);
                    }
                }
            }
        }
    }
}

#define AGA(u)                                  \
    a0 += bflo(u.x); a1 += bfhi(u.x);           \
    a2 += bflo(u.y); a3 += bfhi(u.y);           \
    a4 += bflo(u.z); a5 += bfhi(u.z);           \
    a6 += bflo(u.w); a7 += bfhi(u.w);
#define AGC(u)                                  \
    c0 += bflo(u.x); c1 += bfhi(u.x);           \
    c2 += bflo(u.y); c3 += bfhi(u.y);           \
    c4 += bflo(u.z); c5 += bfhi(u.z);           \
    c6 += bflo(u.w); c7 += bfhi(u.w);

// k_aggln: one 16-lane quad per node. Per relation r: gather pre-transformed
// rows hr[r][src], mean; sum over r; + root row + bias; LN + relu (+residual);
// write h in place (safe: only own row touched) or final fp32 out.
__global__ __launch_bounds__(256) void k_aggln(const unsigned* __restrict__ hr,
                                               unsigned* __restrict__ h32,
                                               const int* __restrict__ adj,
                                               const int* __restrict__ rowstart,
                                               const float* __restrict__ bias,
                                               const float* __restrict__ gamma,
                                               const float* __restrict__ beta,
                                               float* __restrict__ out_f,
                                               int add_res, int last) {
    int n = (blockIdx.x * 256 + threadIdx.x) >> 4;   // grid exact: 3125*256/16
    int l15 = threadIdx.x & 15;

    float t0 = 0.f, t1 = 0.f, t2 = 0.f, t3 = 0.f,
          t4 = 0.f, t5 = 0.f, t6 = 0.f, t7 = 0.f;

    for (int r = 0; r < NR; r++) {
        int seg = r * NN + n;
        int st = rowstart[seg], en = rowstart[seg + 1];
        st = st < 0 ? 0 : st;
        en = en > NE ? NE : en;
        const unsigned* T = hr + (size_t)r * NN * 64;

        float a0 = 0.f, a1 = 0.f, a2 = 0.f, a3 = 0.f,
              a4 = 0.f, a5 = 0.f, a6 = 0.f, a7 = 0.f;
        float c0 = 0.f, c1 = 0.f, c2 = 0.f, c3 = 0.f,
              c4 = 0.f, c5 = 0.f, c6 = 0.f, c7 = 0.f;
        int p = st;
        for (; p + 3 < en; p += 4) {
            unsigned s0 = (unsigned)adj[p],     s1 = (unsigned)adj[p + 1];
            unsigned s2 = (unsigned)adj[p + 2], s3 = (unsigned)adj[p + 3];
            s0 = s0 < NN ? s0 : NN - 1;
            s1 = s1 < NN ? s1 : NN - 1;
            s2 = s2 < NN ? s2 : NN - 1;
            s3 = s3 < NN ? s3 : NN - 1;
            uint4 u0 = *(const uint4*)&T[(size_t)s0 * 64 + l15 * 4];
            uint4 u1 = *(const uint4*)&T[(size_t)s1 * 64 + l15 * 4];
            uint4 u2 = *(const uint4*)&T[(size_t)s2 * 64 + l15 * 4];
            uint4 u3 = *(const uint4*)&T[(size_t)s3 * 64 + l15 * 4];
            AGA(u0) AGC(u1) AGA(u2) AGC(u3)
        }
        for (; p < en; p++) {
            unsigned s0 = (unsigned)adj[p];
            s0 = s0 < NN ? s0 : NN - 1;
            uint4 u0 = *(const uint4*)&T[(size_t)s0 * 64 + l15 * 4];
            AGA(u0)
        }
        int d = en - st;
        float sc = 1.0f / (float)(d > 1 ? d : 1);
        t0 += (a0 + c0) * sc; t1 += (a1 + c1) * sc;
        t2 += (a2 + c2) * sc; t3 += (a3 + c3) * sc;
        t4 += (a4 + c4) * sc; t5 += (a5 + c5) * sc;
        t6 += (a6 + c6) * sc; t7 += (a7 + c7) * sc;
    }

    // root row + bias
    {
        uint4 u = *(const uint4*)&hr[((size_t)8 * NN + n) * 64 + l15 * 4];
        t0 += bflo(u.x); t1 += bfhi(u.x);
        t2 += bflo(u.y); t3 += bfhi(u.y);
        t4 += bflo(u.z); t5 += bfhi(u.z);
        t6 += bflo(u.w); t7 += bfhi(u.w);
    }
    int f0 = 8 * l15;
    {
        float4 b0 = *(const float4*)&bias[f0];
        float4 b1 = *(const float4*)&bias[f0 + 4];
        t0 += b0.x; t1 += b0.y; t2 += b0.z; t3 += b0.w;
        t4 += b1.x; t5 += b1.y; t6 += b1.z; t7 += b1.w;
    }

    // LN across 128 feats: in-lane 8-sum + quad shfl reduce (xor<16 stays in quad)
    float s = t0 + t1 + t2 + t3 + t4 + t5 + t6 + t7;
#pragma unroll
    for (int off = 1; off < 16; off <<= 1) s += __shfl_xor(s, off, 64);
    float mu = s * (1.0f / ND);
    float e0 = t0 - mu, e1 = t1 - mu, e2 = t2 - mu, e3 = t3 - mu,
          e4 = t4 - mu, e5 = t5 - mu, e6 = t6 - mu, e7 = t7 - mu;
    float vs = e0 * e0 + e1 * e1 + e2 * e2 + e3 * e3 +
               e4 * e4 + e5 * e5 + e6 * e6 + e7 * e7;
#pragma unroll
    for (int off = 1; off < 16; off <<= 1) vs += __shfl_xor(vs, off, 64);
    float rr = rsqrtf(vs * (1.0f / ND) + LN_EPS);

    float4 g0 = *(const float4*)&gamma[f0];
    float4 g1 = *(const float4*)&gamma[f0 + 4];
    float4 be0 = *(const float4*)&beta[f0];
    float4 be1 = *(const float4*)&beta[f0 + 4];
    float o0 = fmaxf(e0 * rr * g0.x + be0.x, 0.0f);
    float o1 = fmaxf(e1 * rr * g0.y + be0.y, 0.0f);
    float o2 = fmaxf(e2 * rr * g0.z + be0.z, 0.0f);
    float o3 = fmaxf(e3 * rr * g0.w + be0.w, 0.0f);
    float o4 = fmaxf(e4 * rr * g1.x + be1.x, 0.0f);
    float o5 = fmaxf(e5 * rr * g1.y + be1.y, 0.0f);
    float o6 = fmaxf(e6 * rr * g1.z + be1.z, 0.0f);
    float o7 = fmaxf(e7 * rr * g1.w + be1.w, 0.0f);

    if (add_res) {
        uint4 u = *(const uint4*)&h32[(size_t)n * 64 + l15 * 4];
        o0 += bflo(u.x); o1 += bfhi(u.x);
        o2 += bflo(u.y); o3 += bfhi(u.y);
        o4 += bflo(u.z); o5 += bfhi(u.z);
        o6 += bflo(u.w); o7 += bfhi(u.w);
    }
    if (last) {
        *(float4*)&out_f[(size_t)n * ND + f0] = make_float4(o0, o1, o2, o3);
        *(float4*)&out_f[(size_t)n * ND + f0 + 4] = make_float4(o4, o5, o6, o7);
    } else {
        uint4 w;
        w.x = pack2(o0, o1); w.y = pack2(o2, o3);
        w.z = pack2(o4, o5); w.w = pack2(o6, o7);
        *(uint4*)&h32[(size_t)n * 64 + l15 * 4] = w;
    }
}

// ---------- FALLBACK PATH (ws too small): proven round-2 agg+gemm ----------

__global__ __launch_bounds__(256) void k_agg(const unsigned* __restrict__ h32,
                                             const int* __restrict__ adj,
                                             const int* __restrict__ rowstart,
                                             unsigned* __restrict__ S) {
    int q = (blockIdx.x * 256 + threadIdx.x) >> 4;
    int l15 = threadIdx.x & 15;
    int r = q / NN;
    int n = q - r * NN;
    int st = rowstart[q], en = rowstart[q + 1];
    st = st < 0 ? 0 : st;
    en = en > NE ? NE : en;
    float a0 = 0.f, a1 = 0.f, a2 = 0.f, a3 = 0.f,
          a4 = 0.f, a5 = 0.f, a6 = 0.f, a7 = 0.f;
    float c0 = 0.f, c1 = 0.f, c2 = 0.f, c3 = 0.f,
          c4 = 0.f, c5 = 0.f, c6 = 0.f, c7 = 0.f;
    int p = st;
    for (; p + 3 < en; p += 4) {
        unsigned s0 = (unsigned)adj[p],     s1 = (unsigned)adj[p + 1];
        unsigned s2 = (unsigned)adj[p + 2], s3 = (unsigned)adj[p + 3];
        s0 = s0 < NN ? s0 : NN - 1;
        s1 = s1 < NN ? s1 : NN - 1;
        s2 = s2 < NN ? s2 : NN - 1;
        s3 = s3 < NN ? s3 : NN - 1;
        uint4 u0 = *(const uint4*)&h32[(size_t)s0 * 64 + l15 * 4];
        uint4 u1 = *(const uint4*)&h32[(size_t)s1 * 64 + l15 * 4];
        uint4 u2 = *(const uint4*)&h32[(size_t)s2 * 64 + l15 * 4];
        uint4 u3 = *(const uint4*)&h32[(size_t)s3 * 64 + l15 * 4];
        AGA(u0) AGC(u1) AGA(u2) AGC(u3)
    }
    for (; p < en; p++) {
        unsigned s0 = (unsigned)adj[p];
        s0 = s0 < NN ? s0 : NN - 1;
        uint4 u0 = *(const uint4*)&h32[(size_t)s0 * 64 + l15 * 4];
        AGA(u0)
    }
    int d = en - st;
    float sc = 1.0f / (float)(d > 1 ? d : 1);
    a0 = (a0 + c0) * sc; a1 = (a1 + c1) * sc;
    a2 = (a2 + c2) * sc; a3 = (a3 + c3) * sc;
    a4 = (a4 + c4) * sc; a5 = (a5 + c5) * sc;
    a6 = (a6 + c6) * sc; a7 = (a7 + c7) * sc;
    uint4v w;
    w.x = pack2(a0, a1); w.y = pack2(a2, a3);
    w.z = pack2(a4, a5); w.w = pack2(a6, a7);
    __builtin_nontemporal_store(w, (uint4v*)&S[(size_t)n * 512 + r * 64 + l15 * 4]);
}

__global__ __launch_bounds__(256) void k_gemm(const unsigned* __restrict__ S,
                                              unsigned* __restrict__ h32,
                                              const unsigned short* __restrict__ wrel,
                                              const unsigned short* __restrict__ wroot,
                                              const float* __restrict__ bias,
                                              const float* __restrict__ gamma,
                                              const float* __restrict__ beta,
                                              float* __restrict__ out_f,
                                              int add_res, int last) {
    __shared__ char smraw[4 * 16 * PADF * 4];
    float* SLF = (float*)smraw;
    uint4* SB4 = (uint4*)smraw;
    const unsigned short* SBs = (const unsigned short*)smraw;

    int tid = threadIdx.x;
    int wave = tid >> 6, lane = tid & 63;
    int quad = lane >> 4, l15 = lane & 15;
    int w0 = blockIdx.x * 64 + wave * 16;
    int gi = w0 + l15; gi = gi < NN ? gi : NN - 1;
    float* WF = SLF + wave * 16 * PADF;

    float4v acc[8];
#pragma unroll
    for (int i = 0; i < 8; i++) acc[i] = (float4v){0.f, 0.f, 0.f, 0.f};

    const unsigned* Sr = S + (size_t)gi * 512;
    for (int r = 0; r < NR; r++) {
        short8 afr[4];
#pragma unroll
        for (int kk = 0; kk < 4; kk++)
            afr[kk] = *(const short8*)&Sr[r * 64 + kk * 16 + quad * 4];
        __syncthreads();
        {
            const uint4* Wg = (const uint4*)(wrel + (size_t)r * 16384);
#pragma unroll
            for (int i = 0; i < 8; i++) SB4[tid + 256 * i] = Wg[tid + 256 * i];
        }
        __syncthreads();
#pragma unroll
        for (int kk = 0; kk < 4; kk++) {
#pragma unroll
            for (int ft = 0; ft < 8; ft++) {
                short8 bf = *(const short8*)&SBs[((kk * 8 + ft) * 64 + lane) * 8];
                acc[ft] = __builtin_amdgcn_mfma_f32_16x16x32_bf16(afr[kk], bf, acc[ft], 0, 0, 0);
            }
        }
    }
    {
        const unsigned* Hr = h32 + (size_t)gi * 64;
        short8 afr[4];
#pragma unroll
        for (int kk = 0; kk < 4; kk++)
            afr[kk] = *(const short8*)&Hr[kk * 16 + quad * 4];
        __syncthreads();
        {
            const uint4* Wg = (const uint4*)wroot;
#pragma unroll
            for (int i = 0; i < 8; i++) SB4[tid + 256 * i] = Wg[tid + 256 * i];
        }
        __syncthreads();
#pragma unroll
        for (int kk = 0; kk < 4; kk++) {
#pragma unroll
            for (int ft = 0; ft < 8; ft++) {
                short8 bf = *(const short8*)&SBs[((kk * 8 + ft) * 64 + lane) * 8];
                acc[ft] = __builtin_amdgcn_mfma_f32_16x16x32_bf16(afr[kk], bf, acc[ft], 0, 0, 0);
            }
        }
    }
    __syncthreads();

#pragma unroll
    for (int ft = 0; ft < 8; ft++)
#pragma unroll
        for (int rg = 0; rg < 4; rg++)
            WF[(quad * 4 + rg) * PADF + ft * 16 + l15] = acc[ft][rg];

    float2 bia = *(const float2*)&bias[2 * lane];
    float2 gam = *(const float2*)&gamma[2 * lane];
    float2 bet = *(const float2*)&beta[2 * lane];

    for (int i = 0; i < 16; i++) {
        int g = w0 + i;
        if (g >= NN) continue;
        float v0 = WF[i * PADF + 2 * lane] + bia.x;
        float v1 = WF[i * PADF + 2 * lane + 1] + bia.y;
        float s = v0 + v1;
#pragma unroll
        for (int off = 32; off > 0; off >>= 1) s += __shfl_xor(s, off, 64);
        float mu = s * (1.0f / ND);
        float e0 = v0 - mu, e1 = v1 - mu;
        float vs = e0 * e0 + e1 * e1;
#pragma unroll
        for (int off = 32; off > 0; off >>= 1) vs += __shfl_xor(vs, off, 64);
        float rr = rsqrtf(vs * (1.0f / ND) + LN_EPS);
        float o0 = fmaxf(e0 * rr * gam.x + bet.x, 0.0f);
        float o1 = fmaxf(e1 * rr * gam.y + bet.y, 0.0f);
        if (add_res) {
            unsigned u = h32[(size_t)g * 64 + lane];
            o0 += bflo(u);
            o1 += bfhi(u);
        }
        if (last) {
            *(float2*)&out_f[(size_t)g * ND + 2 * lane] = make_float2(o0, o1);
        } else {
            h32[(size_t)g * 64 + lane] = pack2(o0, o1);
        }
    }
}

extern "C" void kernel_launch(void* const* d_in, const int* in_sizes, int n_in,
                              void* d_out, int out_size, void* d_ws, size_t ws_size,
                              hipStream_t stream) {
    const int*   x      = (const int*)d_in[0];
    const int*   ei     = (const int*)d_in[1];
    const int*   et     = (const int*)d_in[2];
    const float* emb    = (const float*)d_in[3];
    const float* w_rel  = (const float*)d_in[4];
    const float* w_root = (const float*)d_in[5];
    const float* bias   = (const float*)d_in[6];
    const float* gamma  = (const float*)d_in[7];
    const float* beta   = (const float*)d_in[8];
    float* out = (float*)d_out;

    char* ws = (char*)d_ws;
    unsigned* h        = (unsigned*)(ws + WS_H);     // 12.8 MB bf16x2 rows
    int*      cnt      = (int*)     (ws + WS_CNT);   // 1.6 MB
    int*      rowstart = (int*)     (ws + WS_ROW);   // 1.6 MB + 4
    int*      bsum     = (int*)     (ws + WS_BSUM);
    int*      boff     = (int*)     (ws + WS_BOFF);
    int*      adj      = (int*)     (ws + WS_ADJ);   // 6.4 MB
    unsigned short* wb = (unsigned short*)(ws + WS_WB);  // 884736 B
    unsigned* big      = (unsigned*)(ws + WS_BIG);   // hr 115.2 MB | S 102.4 MB

    const int* src = ei;
    const int* dst = ei + NE;

    k_prep0<<<(PREP_TOT + 255) / 256, 256, 0, stream>>>(x, emb, w_rel, w_root,
                                                        cnt, h, wb);
    k_count<<<(NE / 4 + 255) / 256, 256, 0, stream>>>(dst, et, cnt);
    k_scan1<<<NB, 256, 0, stream>>>(cnt, rowstart, bsum);
    k_scan2<<<1, 256, 0, stream>>>(bsum, boff);
    k_scan3<<<(RN + 255) / 256, 256, 0, stream>>>(rowstart, boff);
    k_fill<<<(NE / 4 + 255) / 256, 256, 0, stream>>>(src, dst, et, rowstart, cnt, adj);

    if (ws_size >= WS_NEED_NEW) {
        for (int l = 0; l < NL; l++) {
            k_mm<<<(NN + 63) / 64, 256, 0, stream>>>(
                h, wb + (size_t)l * 8 * 16384, wb + (size_t)(24 + l) * 16384, big);
            k_aggln<<<NN * 16 / 256, 256, 0, stream>>>(
                big, h, adj, rowstart,
                bias + l * ND, gamma + l * ND, beta + l * ND,
                out, l > 0, l == NL - 1);
        }
    } else {
        for (int l = 0; l < NL; l++) {
            k_agg<<<RN * 16 / 256, 256, 0, stream>>>(h, adj, rowstart, big);
            k_gemm<<<(NN + 63) / 64, 256, 0, stream>>>(
                big, h,
                wb + (size_t)l * 8 * 16384, wb + (size_t)(24 + l) * 16384,
                bias + l * ND, gamma + l * ND, beta + l * ND,
                out, l > 0, l == NL - 1);
        }
    }
}

// Round 4
// 626.351 us; speedup vs baseline: 1.1663x; 1.1663x over previous
//
#include <hip/hip_runtime.h>

#define NN 50000
#define NE 1600000
#define NR 8
#define ND 128
#define NL 3
#define RN (NR * NN)
#define SCAN_BLK 1024
#define NB ((RN + SCAN_BLK - 1) / SCAN_BLK)  // 391
#define LN_EPS 1e-5f
#define PADF 132   // f32 elems per epilogue scratch row (8448 B per wave region)

// fused prep kernel region sizes
#define PREP_G (NN * 64)        // gather dwords
#define PREP_W (27 * 16384)     // wprep elems
#define PREP_TOT (RN + PREP_G + PREP_W)

// workspace layout
#define WS_H    0
#define WS_CNT  12800000
#define WS_ROW  14400000
#define WS_BSUM 16000064
#define WS_BOFF 16002048
#define WS_ADJ  16004096
#define WS_WB   22404096
#define WS_BIG  23288832
#define WS_NEED_NEW (23288832ULL + 9ULL * NN * 256)   // hr = 9 tables -> 138.5 MB

typedef __attribute__((ext_vector_type(8))) short short8;
typedef __attribute__((ext_vector_type(4))) float float4v;
typedef __attribute__((ext_vector_type(4))) unsigned uint4v;

__device__ __forceinline__ float bflo(unsigned u) { return __uint_as_float(u << 16); }
__device__ __forceinline__ float bfhi(unsigned u) { return __uint_as_float(u & 0xFFFF0000u); }
__device__ __forceinline__ unsigned f2bf(float f) {
    unsigned u = __float_as_uint(f);
    return (u + 0x7FFFu + ((u >> 16) & 1u)) >> 16;   // RNE
}
__device__ __forceinline__ unsigned pack2(float lo, float hi) {
    return f2bf(lo) | (f2bf(hi) << 16);
}

// fused: cnt zero | h gather (row-major bf16x2) | weight prep (B-frag layout)
__global__ __launch_bounds__(256) void k_prep0(const int* __restrict__ x,
                                               const float* __restrict__ emb,
                                               const float* __restrict__ w_rel,
                                               const float* __restrict__ w_root,
                                               int* __restrict__ cnt,
                                               unsigned* __restrict__ h,
                                               unsigned short* __restrict__ wb) {
    int i = blockIdx.x * 256 + threadIdx.x;
    if (i < RN) {
        cnt[i] = 0;
        return;
    }
    i -= RN;
    if (i < PREP_G) {
        int n = i >> 6, dw = i & 63;
        float2 v = *(const float2*)&emb[(size_t)x[n] * ND + 2 * dw];
        h[i] = pack2(v.x, v.y);
        return;
    }
    i -= PREP_G;
    if (i >= PREP_W) return;
    int m = i >> 14;
    int idx = i & 16383;
    int j = idx & 7;
    int lane = (idx >> 3) & 63;
    int ft = (idx >> 9) & 7;
    int kk = idx >> 12;
    int row = kk * 32 + (lane >> 4) * 8 + j;
    int col = ft * 16 + (lane & 15);
    const float* W = (m < 24) ? (w_rel + (size_t)m * 16384)
                              : (w_root + (size_t)(m - 24) * 16384);
    wb[i] = (unsigned short)f2bf(W[row * ND + col]);
}

__global__ __launch_bounds__(256) void k_count(const int* __restrict__ dst,
                                               const int* __restrict__ et,
                                               int* __restrict__ cnt) {
    int i = blockIdx.x * 256 + threadIdx.x;
    if (i >= NE / 4) return;
    int4 d4 = ((const int4*)dst)[i];
    int4 t4 = ((const int4*)et)[i];
    atomicAdd(&cnt[t4.x * NN + d4.x], 1);
    atomicAdd(&cnt[t4.y * NN + d4.y], 1);
    atomicAdd(&cnt[t4.z * NN + d4.z], 1);
    atomicAdd(&cnt[t4.w * NN + d4.w], 1);
}

// scan over cnt -> rowstart (exclusive)
__global__ __launch_bounds__(256) void k_scan1(const int* __restrict__ cnt,
                                               int* __restrict__ rowstart,
                                               int* __restrict__ bsum) {
    __shared__ int tmp[256];
    int t = threadIdx.x;
    int base = blockIdx.x * SCAN_BLK + t * 4;
    int v[4];
#pragma unroll
    for (int i = 0; i < 4; i++) v[i] = (base + i < RN) ? cnt[base + i] : 0;
    int local = v[0] + v[1] + v[2] + v[3];
    tmp[t] = local;
    __syncthreads();
    for (int off = 1; off < 256; off <<= 1) {
        int x = (t >= off) ? tmp[t - off] : 0;
        __syncthreads();
        tmp[t] += x;
        __syncthreads();
    }
    int run = tmp[t] - local;
    if (t == 255) bsum[blockIdx.x] = tmp[t];
#pragma unroll
    for (int i = 0; i < 4; i++) {
        if (base + i < RN) rowstart[base + i] = run;
        run += v[i];
    }
}

__global__ __launch_bounds__(256) void k_scan2(const int* __restrict__ bsum,
                                               int* __restrict__ boff) {
    __shared__ int tmp[256];
    int t = threadIdx.x;
    int v0 = (2 * t < NB) ? bsum[2 * t] : 0;
    int v1 = (2 * t + 1 < NB) ? bsum[2 * t + 1] : 0;
    int local = v0 + v1;
    tmp[t] = local;
    __syncthreads();
    for (int off = 1; off < 256; off <<= 1) {
        int x = (t >= off) ? tmp[t - off] : 0;
        __syncthreads();
        tmp[t] += x;
        __syncthreads();
    }
    int excl = tmp[t] - local;
    if (2 * t < NB) boff[2 * t] = excl;
    if (2 * t + 1 < NB) boff[2 * t + 1] = excl + v0;
}

__global__ __launch_bounds__(256) void k_scan3(int* __restrict__ rowstart,
                                               const int* __restrict__ boff) {
    int i = blockIdx.x * 256 + threadIdx.x;
    if (i < RN) rowstart[i] += boff[i >> 10];
    if (i == 0) rowstart[RN] = NE;
}

// Plain stores (nt-store regressed 88->110: no L2 merging, full latency per
// store; WRITE_SIZE is line-count-driven either way). This is the scatter floor.
__global__ __launch_bounds__(256) void k_fill(const int* __restrict__ src,
                                              const int* __restrict__ dst,
                                              const int* __restrict__ et,
                                              const int* __restrict__ rowstart,
                                              int* __restrict__ cnt,
                                              int* __restrict__ adj) {
    int i = blockIdx.x * 256 + threadIdx.x;
    if (i >= NE / 4) return;
    int4 s4 = ((const int4*)src)[i];
    int4 d4 = ((const int4*)dst)[i];
    int4 t4 = ((const int4*)et)[i];
    int seg, c;
    seg = t4.x * NN + d4.x; c = atomicSub(&cnt[seg], 1); adj[rowstart[seg] + c - 1] = s4.x;
    seg = t4.y * NN + d4.y; c = atomicSub(&cnt[seg], 1); adj[rowstart[seg] + c - 1] = s4.y;
    seg = t4.z * NN + d4.z; c = atomicSub(&cnt[seg], 1); adj[rowstart[seg] + c - 1] = s4.z;
    seg = t4.w * NN + d4.w; c = atomicSub(&cnt[seg], 1); adj[rowstart[seg] + c - 1] = s4.w;
}

// ---------- transform-first path: hr[m] = h @ W_m, then gather+LN ----------

// k_mm epilogue v2: round-3's nt parity-stores wrote each 64B line as two 32B
// halves with no L2 merge -> WRITE_SIZE 235 MB (2x). Now: pack bf16x2
// in-register (shfl_xor(1) parity trick), transpose through wave-private LDS
// (no barrier needed: same-wave ds ordering via lgkmcnt), emit plain uint4
// stores -- each instruction writes 4 complete rows = 1 KB contiguous.
__global__ __launch_bounds__(256) void k_mm(const unsigned* __restrict__ h32,
                                            const unsigned short* __restrict__ wrel,
                                            const unsigned short* __restrict__ wroot,
                                            unsigned* __restrict__ hr) {
    __shared__ uint4 SB4[2048];                      // 32 KB B stage
    __shared__ unsigned TR[4][16][66];               // 16.5 KB, pad 66: wr conflict-free
    const unsigned short* SBs = (const unsigned short*)SB4;

    int tid = threadIdx.x;
    int wave = tid >> 6, lane = tid & 63;
    int quad = lane >> 4, l15 = lane & 15;
    int w0w = blockIdx.x * 64 + wave * 16;
    int gi = w0w + l15; gi = gi < NN ? gi : NN - 1;
    int pr = l15 & 1;

    const unsigned* Hrow = h32 + (size_t)gi * 64;
    short8 afr[4];
#pragma unroll
    for (int kk = 0; kk < 4; kk++)
        afr[kk] = *(const short8*)&Hrow[kk * 16 + quad * 4];

    for (int m = 0; m < 9; m++) {
        const unsigned short* W = (m < 8) ? (wrel + (size_t)m * 16384) : wroot;
        __syncthreads();                             // prev m's SB reads done
        {
            const uint4* Wg = (const uint4*)W;
#pragma unroll
            for (int i = 0; i < 8; i++) SB4[tid + 256 * i] = Wg[tid + 256 * i];
        }
        __syncthreads();

        float4v acc[8];
#pragma unroll
        for (int i = 0; i < 8; i++) acc[i] = (float4v){0.f, 0.f, 0.f, 0.f};
#pragma unroll
        for (int kk = 0; kk < 4; kk++) {
#pragma unroll
            for (int ft = 0; ft < 8; ft++) {
                short8 bf = *(const short8*)&SBs[((kk * 8 + ft) * 64 + lane) * 8];
                acc[ft] = __builtin_amdgcn_mfma_f32_16x16x32_bf16(afr[kk], bf, acc[ft], 0, 0, 0);
            }
        }

        // pack + wave-private transpose: lane with (ft&1)==pr produces dword
        // a=l15>>1 of rows quad*4+rg (all 64 lanes produce 16 dwords each)
#pragma unroll
        for (int ft = 0; ft < 8; ft++) {
            float4v part;
#pragma unroll
            for (int rg = 0; rg < 4; rg++) part[rg] = __shfl_xor(acc[ft][rg], 1, 64);
            if ((ft & 1) == pr) {
                int a = l15 >> 1;
#pragma unroll
                for (int rg = 0; rg < 4; rg++) {
                    float lo = pr ? part[rg] : acc[ft][rg];   // even col
                    float hi = pr ? acc[ft][rg] : part[rg];   // odd col
                    TR[wave][quad * 4 + rg][ft * 8 + a] = pack2(lo, hi);
                }
            }
        }
        // read back row-linear; 4 complete rows (1 KB contiguous) per pass
        unsigned* hrm = hr + (size_t)m * NN * 64;
#pragma unroll
        for (int ps = 0; ps < 4; ps++) {
            int ri = ps * 4 + quad;
            uint4 v = *(const uint4*)&TR[wave][ri][l15 * 4];
            int row = w0w + ri;
            if (row < NN)
                *(uint4*)&hrm[(size_t)row * 64 + l15 * 4] = v;
        }
    }
}

#define AGA(u)                                  \
    a0 += bflo(u.x); a1 += bfhi(u.x);           \
    a2 += bflo(u.y); a3 += bfhi(u.y);           \
    a4 += bflo(u.z); a5 += bfhi(u.z);           \
    a6 += bflo(u.w); a7 += bfhi(u.w);
#define AGC(u)                                  \
    c0 += bflo(u.x); c1 += bfhi(u.x);           \
    c2 += bflo(u.y); c3 += bfhi(u.y);           \
    c4 += bflo(u.z); c5 += bfhi(u.z);           \
    c6 += bflo(u.w); c7 += bfhi(u.w);

// k_aggln: one 16-lane quad per node. Per relation r: gather pre-transformed
// rows hr[r][src], mean; sum over r; + root row + bias; LN + relu (+residual);
// write h in place (safe: only own row touched) or final fp32 out.
__global__ __launch_bounds__(256) void k_aggln(const unsigned* __restrict__ hr,
                                               unsigned* __restrict__ h32,
                                               const int* __restrict__ adj,
                                               const int* __restrict__ rowstart,
                                               const float* __restrict__ bias,
                                               const float* __restrict__ gamma,
                                               const float* __restrict__ beta,
                                               float* __restrict__ out_f,
                                               int add_res, int last) {
    int n = (blockIdx.x * 256 + threadIdx.x) >> 4;   // grid exact: 3125*256/16
    int l15 = threadIdx.x & 15;

    float t0 = 0.f, t1 = 0.f, t2 = 0.f, t3 = 0.f,
          t4 = 0.f, t5 = 0.f, t6 = 0.f, t7 = 0.f;

    for (int r = 0; r < NR; r++) {
        int seg = r * NN + n;
        int st = rowstart[seg], en = rowstart[seg + 1];
        st = st < 0 ? 0 : st;
        en = en > NE ? NE : en;
        const unsigned* T = hr + (size_t)r * NN * 64;

        float a0 = 0.f, a1 = 0.f, a2 = 0.f, a3 = 0.f,
              a4 = 0.f, a5 = 0.f, a6 = 0.f, a7 = 0.f;
        float c0 = 0.f, c1 = 0.f, c2 = 0.f, c3 = 0.f,
              c4 = 0.f, c5 = 0.f, c6 = 0.f, c7 = 0.f;
        int p = st;
        for (; p + 3 < en; p += 4) {
            unsigned s0 = (unsigned)adj[p],     s1 = (unsigned)adj[p + 1];
            unsigned s2 = (unsigned)adj[p + 2], s3 = (unsigned)adj[p + 3];
            s0 = s0 < NN ? s0 : NN - 1;
            s1 = s1 < NN ? s1 : NN - 1;
            s2 = s2 < NN ? s2 : NN - 1;
            s3 = s3 < NN ? s3 : NN - 1;
            uint4 u0 = *(const uint4*)&T[(size_t)s0 * 64 + l15 * 4];
            uint4 u1 = *(const uint4*)&T[(size_t)s1 * 64 + l15 * 4];
            uint4 u2 = *(const uint4*)&T[(size_t)s2 * 64 + l15 * 4];
            uint4 u3 = *(const uint4*)&T[(size_t)s3 * 64 + l15 * 4];
            AGA(u0) AGC(u1) AGA(u2) AGC(u3)
        }
        for (; p < en; p++) {
            unsigned s0 = (unsigned)adj[p];
            s0 = s0 < NN ? s0 : NN - 1;
            uint4 u0 = *(const uint4*)&T[(size_t)s0 * 64 + l15 * 4];
            AGA(u0)
        }
        int d = en - st;
        float sc = 1.0f / (float)(d > 1 ? d : 1);
        t0 += (a0 + c0) * sc; t1 += (a1 + c1) * sc;
        t2 += (a2 + c2) * sc; t3 += (a3 + c3) * sc;
        t4 += (a4 + c4) * sc; t5 += (a5 + c5) * sc;
        t6 += (a6 + c6) * sc; t7 += (a7 + c7) * sc;
    }

    // root row + bias
    {
        uint4 u = *(const uint4*)&hr[((size_t)8 * NN + n) * 64 + l15 * 4];
        t0 += bflo(u.x); t1 += bfhi(u.x);
        t2 += bflo(u.y); t3 += bfhi(u.y);
        t4 += bflo(u.z); t5 += bfhi(u.z);
        t6 += bflo(u.w); t7 += bfhi(u.w);
    }
    int f0 = 8 * l15;
    {
        float4 b0 = *(const float4*)&bias[f0];
        float4 b1 = *(const float4*)&bias[f0 + 4];
        t0 += b0.x; t1 += b0.y; t2 += b0.z; t3 += b0.w;
        t4 += b1.x; t5 += b1.y; t6 += b1.z; t7 += b1.w;
    }

    // LN across 128 feats: in-lane 8-sum + quad shfl reduce (xor<16 stays in quad)
    float s = t0 + t1 + t2 + t3 + t4 + t5 + t6 + t7;
#pragma unroll
    for (int off = 1; off < 16; off <<= 1) s += __shfl_xor(s, off, 64);
    float mu = s * (1.0f / ND);
    float e0 = t0 - mu, e1 = t1 - mu, e2 = t2 - mu, e3 = t3 - mu,
          e4 = t4 - mu, e5 = t5 - mu, e6 = t6 - mu, e7 = t7 - mu;
    float vs = e0 * e0 + e1 * e1 + e2 * e2 + e3 * e3 +
               e4 * e4 + e5 * e5 + e6 * e6 + e7 * e7;
#pragma unroll
    for (int off = 1; off < 16; off <<= 1) vs += __shfl_xor(vs, off, 64);
    float rr = rsqrtf(vs * (1.0f / ND) + LN_EPS);

    float4 g0 = *(const float4*)&gamma[f0];
    float4 g1 = *(const float4*)&gamma[f0 + 4];
    float4 be0 = *(const float4*)&beta[f0];
    float4 be1 = *(const float4*)&beta[f0 + 4];
    float o0 = fmaxf(e0 * rr * g0.x + be0.x, 0.0f);
    float o1 = fmaxf(e1 * rr * g0.y + be0.y, 0.0f);
    float o2 = fmaxf(e2 * rr * g0.z + be0.z, 0.0f);
    float o3 = fmaxf(e3 * rr * g0.w + be0.w, 0.0f);
    float o4 = fmaxf(e4 * rr * g1.x + be1.x, 0.0f);
    float o5 = fmaxf(e5 * rr * g1.y + be1.y, 0.0f);
    float o6 = fmaxf(e6 * rr * g1.z + be1.z, 0.0f);
    float o7 = fmaxf(e7 * rr * g1.w + be1.w, 0.0f);

    if (add_res) {
        uint4 u = *(const uint4*)&h32[(size_t)n * 64 + l15 * 4];
        o0 += bflo(u.x); o1 += bfhi(u.x);
        o2 += bflo(u.y); o3 += bfhi(u.y);
        o4 += bflo(u.z); o5 += bfhi(u.z);
        o6 += bflo(u.w); o7 += bfhi(u.w);
    }
    if (last) {
        *(float4*)&out_f[(size_t)n * ND + f0] = make_float4(o0, o1, o2, o3);
        *(float4*)&out_f[(size_t)n * ND + f0 + 4] = make_float4(o4, o5, o6, o7);
    } else {
        uint4 w;
        w.x = pack2(o0, o1); w.y = pack2(o2, o3);
        w.z = pack2(o4, o5); w.w = pack2(o6, o7);
        *(uint4*)&h32[(size_t)n * 64 + l15 * 4] = w;
    }
}

// ---------- FALLBACK PATH (ws too small): proven round-2 agg+gemm ----------

__global__ __launch_bounds__(256) void k_agg(const unsigned* __restrict__ h32,
                                             const int* __restrict__ adj,
                                             const int* __restrict__ rowstart,
                                             unsigned* __restrict__ S) {
    int q = (blockIdx.x * 256 + threadIdx.x) >> 4;
    int l15 = threadIdx.x & 15;
    int r = q / NN;
    int n = q - r * NN;
    int st = rowstart[q], en = rowstart[q + 1];
    st = st < 0 ? 0 : st;
    en = en > NE ? NE : en;
    float a0 = 0.f, a1 = 0.f, a2 = 0.f, a3 = 0.f,
          a4 = 0.f, a5 = 0.f, a6 = 0.f, a7 = 0.f;
    float c0 = 0.f, c1 = 0.f, c2 = 0.f, c3 = 0.f,
          c4 = 0.f, c5 = 0.f, c6 = 0.f, c7 = 0.f;
    int p = st;
    for (; p + 3 < en; p += 4) {
        unsigned s0 = (unsigned)adj[p],     s1 = (unsigned)adj[p + 1];
        unsigned s2 = (unsigned)adj[p + 2], s3 = (unsigned)adj[p + 3];
        s0 = s0 < NN ? s0 : NN - 1;
        s1 = s1 < NN ? s1 : NN - 1;
        s2 = s2 < NN ? s2 : NN - 1;
        s3 = s3 < NN ? s3 : NN - 1;
        uint4 u0 = *(const uint4*)&h32[(size_t)s0 * 64 + l15 * 4];
        uint4 u1 = *(const uint4*)&h32[(size_t)s1 * 64 + l15 * 4];
        uint4 u2 = *(const uint4*)&h32[(size_t)s2 * 64 + l15 * 4];
        uint4 u3 = *(const uint4*)&h32[(size_t)s3 * 64 + l15 * 4];
        AGA(u0) AGC(u1) AGA(u2) AGC(u3)
    }
    for (; p < en; p++) {
        unsigned s0 = (unsigned)adj[p];
        s0 = s0 < NN ? s0 : NN - 1;
        uint4 u0 = *(const uint4*)&h32[(size_t)s0 * 64 + l15 * 4];
        AGA(u0)
    }
    int d = en - st;
    float sc = 1.0f / (float)(d > 1 ? d : 1);
    a0 = (a0 + c0) * sc; a1 = (a1 + c1) * sc;
    a2 = (a2 + c2) * sc; a3 = (a3 + c3) * sc;
    a4 = (a4 + c4) * sc; a5 = (a5 + c5) * sc;
    a6 = (a6 + c6) * sc; a7 = (a7 + c7) * sc;
    uint4v w;
    w.x = pack2(a0, a1); w.y = pack2(a2, a3);
    w.z = pack2(a4, a5); w.w = pack2(a6, a7);
    __builtin_nontemporal_store(w, (uint4v*)&S[(size_t)n * 512 + r * 64 + l15 * 4]);
}

__global__ __launch_bounds__(256) void k_gemm(const unsigned* __restrict__ S,
                                              unsigned* __restrict__ h32,
                                              const unsigned short* __restrict__ wrel,
                                              const unsigned short* __restrict__ wroot,
                                              const float* __restrict__ bias,
                                              const float* __restrict__ gamma,
                                              const float* __restrict__ beta,
                                              float* __restrict__ out_f,
                                              int add_res, int last) {
    __shared__ char smraw[4 * 16 * PADF * 4];
    float* SLF = (float*)smraw;
    uint4* SB4 = (uint4*)smraw;
    const unsigned short* SBs = (const unsigned short*)smraw;

    int tid = threadIdx.x;
    int wave = tid >> 6, lane = tid & 63;
    int quad = lane >> 4, l15 = lane & 15;
    int w0 = blockIdx.x * 64 + wave * 16;
    int gi = w0 + l15; gi = gi < NN ? gi : NN - 1;
    float* WF = SLF + wave * 16 * PADF;

    float4v acc[8];
#pragma unroll
    for (int i = 0; i < 8; i++) acc[i] = (float4v){0.f, 0.f, 0.f, 0.f};

    const unsigned* Sr = S + (size_t)gi * 512;
    for (int r = 0; r < NR; r++) {
        short8 afr[4];
#pragma unroll
        for (int kk = 0; kk < 4; kk++)
            afr[kk] = *(const short8*)&Sr[r * 64 + kk * 16 + quad * 4];
        __syncthreads();
        {
            const uint4* Wg = (const uint4*)(wrel + (size_t)r * 16384);
#pragma unroll
            for (int i = 0; i < 8; i++) SB4[tid + 256 * i] = Wg[tid + 256 * i];
        }
        __syncthreads();
#pragma unroll
        for (int kk = 0; kk < 4; kk++) {
#pragma unroll
            for (int ft = 0; ft < 8; ft++) {
                short8 bf = *(const short8*)&SBs[((kk * 8 + ft) * 64 + lane) * 8];
                acc[ft] = __builtin_amdgcn_mfma_f32_16x16x32_bf16(afr[kk], bf, acc[ft], 0, 0, 0);
            }
        }
    }
    {
        const unsigned* Hr = h32 + (size_t)gi * 64;
        short8 afr[4];
#pragma unroll
        for (int kk = 0; kk < 4; kk++)
            afr[kk] = *(const short8*)&Hr[kk * 16 + quad * 4];
        __syncthreads();
        {
            const uint4* Wg = (const uint4*)wroot;
#pragma unroll
            for (int i = 0; i < 8; i++) SB4[tid + 256 * i] = Wg[tid + 256 * i];
        }
        __syncthreads();
#pragma unroll
        for (int kk = 0; kk < 4; kk++) {
#pragma unroll
            for (int ft = 0; ft < 8; ft++) {
                short8 bf = *(const short8*)&SBs[((kk * 8 + ft) * 64 + lane) * 8];
                acc[ft] = __builtin_amdgcn_mfma_f32_16x16x32_bf16(afr[kk], bf, acc[ft], 0, 0, 0);
            }
        }
    }
    __syncthreads();

#pragma unroll
    for (int ft = 0; ft < 8; ft++)
#pragma unroll
        for (int rg = 0; rg < 4; rg++)
            WF[(quad * 4 + rg) * PADF + ft * 16 + l15] = acc[ft][rg];

    float2 bia = *(const float2*)&bias[2 * lane];
    float2 gam = *(const float2*)&gamma[2 * lane];
    float2 bet = *(const float2*)&beta[2 * lane];

    for (int i = 0; i < 16; i++) {
        int g = w0 + i;
        if (g >= NN) continue;
        float v0 = WF[i * PADF + 2 * lane] + bia.x;
        float v1 = WF[i * PADF + 2 * lane + 1] + bia.y;
        float s = v0 + v1;
#pragma unroll
        for (int off = 32; off > 0; off >>= 1) s += __shfl_xor(s, off, 64);
        float mu = s * (1.0f / ND);
        float e0 = v0 - mu, e1 = v1 - mu;
        float vs = e0 * e0 + e1 * e1;
#pragma unroll
        for (int off = 32; off > 0; off >>= 1) vs += __shfl_xor(vs, off, 64);
        float rr = rsqrtf(vs * (1.0f / ND) + LN_EPS);
        float o0 = fmaxf(e0 * rr * gam.x + bet.x, 0.0f);
        float o1 = fmaxf(e1 * rr * gam.y + bet.y, 0.0f);
        if (add_res) {
            unsigned u = h32[(size_t)g * 64 + lane];
            o0 += bflo(u);
            o1 += bfhi(u);
        }
        if (last) {
            *(float2*)&out_f[(size_t)g * ND + 2 * lane] = make_float2(o0, o1);
        } else {
            h32[(size_t)g * 64 + lane] = pack2(o0, o1);
        }
    }
}

extern "C" void kernel_launch(void* const* d_in, const int* in_sizes, int n_in,
                              void* d_out, int out_size, void* d_ws, size_t ws_size,
                              hipStream_t stream) {
    const int*   x      = (const int*)d_in[0];
    const int*   ei     = (const int*)d_in[1];
    const int*   et     = (const int*)d_in[2];
    const float* emb    = (const float*)d_in[3];
    const float* w_rel  = (const float*)d_in[4];
    const float* w_root = (const float*)d_in[5];
    const float* bias   = (const float*)d_in[6];
    const float* gamma  = (const float*)d_in[7];
    const float* beta   = (const float*)d_in[8];
    float* out = (float*)d_out;

    char* ws = (char*)d_ws;
    unsigned* h        = (unsigned*)(ws + WS_H);     // 12.8 MB bf16x2 rows
    int*      cnt      = (int*)     (ws + WS_CNT);   // 1.6 MB
    int*      rowstart = (int*)     (ws + WS_ROW);   // 1.6 MB + 4
    int*      bsum     = (int*)     (ws + WS_BSUM);
    int*      boff     = (int*)     (ws + WS_BOFF);
    int*      adj      = (int*)     (ws + WS_ADJ);   // 6.4 MB
    unsigned short* wb = (unsigned short*)(ws + WS_WB);  // 884736 B
    unsigned* big      = (unsigned*)(ws + WS_BIG);   // hr 115.2 MB | S 102.4 MB

    const int* src = ei;
    const int* dst = ei + NE;

    k_prep0<<<(PREP_TOT + 255) / 256, 256, 0, stream>>>(x, emb, w_rel, w_root,
                                                        cnt, h, wb);
    k_count<<<(NE / 4 + 255) / 256, 256, 0, stream>>>(dst, et, cnt);
    k_scan1<<<NB, 256, 0, stream>>>(cnt, rowstart, bsum);
    k_scan2<<<1, 256, 0, stream>>>(bsum, boff);
    k_scan3<<<(RN + 255) / 256, 256, 0, stream>>>(rowstart, boff);
    k_fill<<<(NE / 4 + 255) / 256, 256, 0, stream>>>(src, dst, et, rowstart, cnt, adj);

    if (ws_size >= WS_NEED_NEW) {
        for (int l = 0; l < NL; l++) {
            k_mm<<<(NN + 63) / 64, 256, 0, stream>>>(
                h, wb + (size_t)l * 8 * 16384, wb + (size_t)(24 + l) * 16384, big);
            k_aggln<<<NN * 16 / 256, 256, 0, stream>>>(
                big, h, adj, rowstart,
                bias + l * ND, gamma + l * ND, beta + l * ND,
                out, l > 0, l == NL - 1);
        }
    } else {
        for (int l = 0; l < NL; l++) {
            k_agg<<<RN * 16 / 256, 256, 0, stream>>>(h, adj, rowstart, big);
            k_gemm<<<(NN + 63) / 64, 256, 0, stream>>>(
                big, h,
                wb + (size_t)l * 8 * 16384, wb + (size_t)(24 + l) * 16384,
                bias + l * ND, gamma + l * ND, beta + l * ND,
                out, l > 0, l == NL - 1);
        }
    }
}